// Round 8
// baseline (247.012 us; speedup 1.0000x reference)
//
#include <hip/hip_runtime.h>
#include <hip/hip_fp16.h>
#include <math.h>

#define EMB_DIM 128
#define FINE_BITS 6
#define FINE_W 64           // nodes per dest bucket (= one K3 block)
#define MAXB 2048           // max coarse buckets (N <= 131072)
#define CHUNK 4096          // edges per scatter block (proven tail-parallel point)
#define MAX_SLACK 4096      // LDS sortedR capacity (slack clamped to this)
#define SB 512              // block threads for K1
#define HIST_EPT 16         // edges per thread in the deg-hist range

// ---------------------------------------------------------------------------
// K1 (fused), three block ranges:
//   [0, nchunks):            col-side coarse scatter (512 thr, int4 loads)
//   [nchunks, nchunks+histB): deg histogram via SINGLE-BATCH global atomics.
//       Round-1 lesson: atomics interleaved in a load loop serialize on
//       in-order vmcnt. Here each thread loads all 16 edges FIRST (4x int4),
//       then fires 16 fire-and-forget atomics and exits — no load ever waits
//       behind an atomic completion.
//   [nchunks+histB, ...):    f32->fp16 embedding convert (BW-bound filler).
// colCur/deg are RELATIVE/zeroed by one memset (adjacent allocations).
__global__ __launch_bounds__(SB) void scatter_cvt_kernel(
    const int* __restrict__ row, const int* __restrict__ col,
    int* __restrict__ colCur, int* __restrict__ deg,
    unsigned int* __restrict__ colBucket,
    const float* __restrict__ emb, __half* __restrict__ emb16, long long n8,
    int slack, int nchunks, int histB, int e) {
    int bid = blockIdx.x;
    int tid = threadIdx.x;
    if (bid >= nchunks + histB) {
        // ---- cvt tail: 8 floats -> 8 halves per thread ----
        long long t = (long long)(bid - nchunks - histB) * SB + tid;
        if (t < n8) {
            const float4* src = (const float4*)(emb) + t * 2;
            float4 a = src[0];
            float4 b = src[1];
            __half h[8];
            h[0] = __float2half(a.x); h[1] = __float2half(a.y);
            h[2] = __float2half(a.z); h[3] = __float2half(a.w);
            h[4] = __float2half(b.x); h[5] = __float2half(b.y);
            h[6] = __float2half(b.z); h[7] = __float2half(b.w);
            ((uint4*)emb16)[t] = *(const uint4*)h;
        }
        return;
    }
    if (bid >= nchunks) {
        // ---- deg histogram: one batch of HIST_EPT edges per thread ----
        long long s0 = ((long long)(bid - nchunks) * SB + tid) * HIST_EPT;
        if (s0 + HIST_EPT <= e) {
            const int4* p = (const int4*)(row + s0);    // 64B-aligned
            int4 a0 = p[0], a1 = p[1], a2 = p[2], a3 = p[3];
            atomicAdd(&deg[a0.x], 1); atomicAdd(&deg[a0.y], 1);
            atomicAdd(&deg[a0.z], 1); atomicAdd(&deg[a0.w], 1);
            atomicAdd(&deg[a1.x], 1); atomicAdd(&deg[a1.y], 1);
            atomicAdd(&deg[a1.z], 1); atomicAdd(&deg[a1.w], 1);
            atomicAdd(&deg[a2.x], 1); atomicAdd(&deg[a2.y], 1);
            atomicAdd(&deg[a2.z], 1); atomicAdd(&deg[a2.w], 1);
            atomicAdd(&deg[a3.x], 1); atomicAdd(&deg[a3.y], 1);
            atomicAdd(&deg[a3.z], 1); atomicAdd(&deg[a3.w], 1);
        } else {
            for (long long i = s0; i < e; ++i) atomicAdd(&deg[row[i]], 1);
        }
        return;
    }
    // ---- col-side coarse scatter (identical to round-7 proven code) ----
    __shared__ int lh[MAXB], lb[MAXB];
    int base = bid * CHUNK;
    int lim = min(base + CHUNK, e);
    int nfull4 = (lim - base) >> 2;            // # of full int4 groups

    for (int t = tid; t < MAXB; t += SB) lh[t] = 0;
    __syncthreads();
    for (int g = tid; g < nfull4; g += SB) {
        int4 c4 = *(const int4*)(col + base + 4 * g);
        atomicAdd(&lh[c4.x >> FINE_BITS], 1);
        atomicAdd(&lh[c4.y >> FINE_BITS], 1);
        atomicAdd(&lh[c4.z >> FINE_BITS], 1);
        atomicAdd(&lh[c4.w >> FINE_BITS], 1);
    }
    for (int i = base + 4 * nfull4 + tid; i < lim; i += SB)
        atomicAdd(&lh[col[i] >> FINE_BITS], 1);
    __syncthreads();
    for (int t = tid; t < MAXB; t += SB)
        lb[t] = lh[t] ? (t * slack + atomicAdd(&colCur[t], lh[t])) : 0;
    __syncthreads();
    for (int t = tid; t < MAXB; t += SB) lh[t] = 0;
    __syncthreads();
    for (int g = tid; g < nfull4; g += SB) {
        int4 c4 = *(const int4*)(col + base + 4 * g);
        int4 r4 = *(const int4*)(row + base + 4 * g);
        #pragma unroll
        for (int k = 0; k < 4; ++k) {
            int c = (&c4.x)[k], r = (&r4.x)[k];
            int cb = c >> FINE_BITS;
            int p = lb[cb] + atomicAdd(&lh[cb], 1);
            if (p < (cb + 1) * slack)
                colBucket[p] = ((unsigned)r << FINE_BITS) | (unsigned)(c & (FINE_W - 1));
        }
    }
    for (int i = base + 4 * nfull4 + tid; i < lim; i += SB) {
        int c = col[i], r = row[i];
        int cb = c >> FINE_BITS;
        int p = lb[cb] + atomicAdd(&lh[cb], 1);
        if (p < (cb + 1) * slack)
            colBucket[p] = ((unsigned)r << FINE_BITS) | (unsigned)(c & (FINE_W - 1));
    }
}

// ---------------------------------------------------------------------------
// K2: dis[i] = rsqrt(1 + deg[i])  (deg complete after K1; +1 = self loop)
__global__ __launch_bounds__(256) void dis_kernel(
    const int* __restrict__ deg, float* __restrict__ dis, int n) {
    int i = blockIdx.x * 256 + threadIdx.x;
    if (i < n) dis[i] = rsqrtf(1.0f + (float)deg[i]);
}

// ---------------------------------------------------------------------------
// K3: bucket gather, register accumulation (round-5/7 proven: 68.5us, VGPR 32).
// One 512-thread block per 64-node bucket:
//   phase 1: in-block counting sort of the bucket's ~1K edges by fine node;
//   phase 2: 64 groups x 8 lanes; group g accumulates node g's contiguous
//            edge range in registers, unroll-2. Self-loop in init (norm=dc^2).
template <bool FP16>
__global__ __launch_bounds__(512) void gather_kernel(
    const __half* __restrict__ emb16, const float* __restrict__ emb,
    const float* __restrict__ dis, const unsigned int* __restrict__ colBucket,
    const int* __restrict__ colCurF, float* __restrict__ out,
    int slack, int n) {
    __shared__ int binCnt[FINE_W];
    __shared__ int binStart[FINE_W];
    __shared__ int binCur[FINE_W];
    __shared__ int sortedR[MAX_SLACK];
    __shared__ float disl[FINE_W];
    int b = blockIdx.x;
    int tid = threadIdx.x;
    int nodeBase = b << FINE_BITS;
    int start = b * slack;
    int cnt = min(colCurF[b], slack);

    if (tid < FINE_W) {
        binCnt[tid] = 0;
        int node = nodeBase + tid;
        disl[tid] = (node < n) ? dis[node] : 0.0f;
    }
    __syncthreads();

    // ---- phase 1a: fine histogram (coalesced global read, int LDS atomics)
    for (int i = tid; i < cnt; i += 512)
        atomicAdd(&binCnt[colBucket[start + i] & (FINE_W - 1)], 1);
    __syncthreads();

    // ---- phase 1b: exclusive scan of 64 bins entirely inside wave 0
    if (tid < FINE_W) {
        int v = binCnt[tid];
        int incl = v;
        #pragma unroll
        for (int d = 1; d < FINE_W; d <<= 1) {
            int u = __shfl_up(incl, d, FINE_W);
            if (tid >= d) incl += u;
        }
        binStart[tid] = incl - v;
        binCur[tid] = incl - v;
    }
    __syncthreads();

    // ---- phase 1c: scatter source ids into node-contiguous LDS order
    for (int i = tid; i < cnt; i += 512) {
        unsigned v = colBucket[start + i];
        int p = atomicAdd(&binCur[v & (FINE_W - 1)], 1);
        sortedR[p] = (int)(v >> FINE_BITS);
    }
    __syncthreads();

    // ---- phase 2: register accumulation, 8 lanes per node, 16 dims/lane
    int g = tid >> 3;        // node within bucket
    int lane = tid & 7;
    int node = nodeBase + g;
    int node_s = (node < n) ? node : 0;
    float dc = disl[g];
    float s = dc * dc;
    float4 acc0, acc1, acc2, acc3;

#define ACCUM_FP16(SRC, NRM)                                                    \
    {                                                                           \
        const uint4* hrow = (const uint4*)(emb16 + (long long)(SRC) * EMB_DIM); \
        uint4 ha = hrow[lane];                                                  \
        uint4 hb = hrow[lane + 8];                                              \
        const __half2* pa = (const __half2*)&ha;                                \
        const __half2* pb = (const __half2*)&hb;                                \
        float2 f0 = __half22float2(pa[0]), f1 = __half22float2(pa[1]);          \
        float2 f2 = __half22float2(pa[2]), f3 = __half22float2(pa[3]);          \
        float2 g0 = __half22float2(pb[0]), g1 = __half22float2(pb[1]);          \
        float2 g2 = __half22float2(pb[2]), g3 = __half22float2(pb[3]);          \
        acc0.x += (NRM) * f0.x; acc0.y += (NRM) * f0.y;                         \
        acc0.z += (NRM) * f1.x; acc0.w += (NRM) * f1.y;                         \
        acc1.x += (NRM) * f2.x; acc1.y += (NRM) * f2.y;                         \
        acc1.z += (NRM) * f3.x; acc1.w += (NRM) * f3.y;                         \
        acc2.x += (NRM) * g0.x; acc2.y += (NRM) * g0.y;                         \
        acc2.z += (NRM) * g1.x; acc2.w += (NRM) * g1.y;                         \
        acc3.x += (NRM) * g2.x; acc3.y += (NRM) * g2.y;                         \
        acc3.z += (NRM) * g3.x; acc3.w += (NRM) * g3.y;                         \
    }

#define ACCUM_FP32(SRC, NRM)                                                    \
    {                                                                           \
        const float4* frow = (const float4*)(emb + (long long)(SRC) * EMB_DIM); \
        float4 v0 = frow[2 * lane];                                             \
        float4 v1 = frow[2 * lane + 1];                                         \
        float4 v2 = frow[16 + 2 * lane];                                        \
        float4 v3 = frow[16 + 2 * lane + 1];                                    \
        acc0.x += (NRM) * v0.x; acc0.y += (NRM) * v0.y;                         \
        acc0.z += (NRM) * v0.z; acc0.w += (NRM) * v0.w;                         \
        acc1.x += (NRM) * v1.x; acc1.y += (NRM) * v1.y;                         \
        acc1.z += (NRM) * v1.z; acc1.w += (NRM) * v1.w;                         \
        acc2.x += (NRM) * v2.x; acc2.y += (NRM) * v2.y;                         \
        acc2.z += (NRM) * v2.z; acc2.w += (NRM) * v2.w;                         \
        acc3.x += (NRM) * v3.x; acc3.y += (NRM) * v3.y;                         \
        acc3.z += (NRM) * v3.z; acc3.w += (NRM) * v3.w;                         \
    }

    // self-loop init: acc = dis^2 * emb[node] (s==0 for padding rows)
    acc0 = acc1 = acc2 = acc3 = float4{0, 0, 0, 0};
    if (FP16) { ACCUM_FP16(node_s, s); } else { ACCUM_FP32(node_s, s); }

    int i = binStart[g];
    int end = i + binCnt[g];
    for (; i + 2 <= end; i += 2) {
        int s0 = sortedR[i], s1 = sortedR[i + 1];
        float n0 = dc * dis[s0];
        float n1 = dc * dis[s1];
        if (FP16) { ACCUM_FP16(s0, n0); ACCUM_FP16(s1, n1); }
        else      { ACCUM_FP32(s0, n0); ACCUM_FP32(s1, n1); }
    }
    if (i < end) {
        int s0 = sortedR[i];
        float n0 = dc * dis[s0];
        if (FP16) { ACCUM_FP16(s0, n0); } else { ACCUM_FP32(s0, n0); }
    }
#undef ACCUM_FP16
#undef ACCUM_FP32

    if (node < n) {
        float4* orow = (float4*)(out + (long long)node * EMB_DIM);
        orow[2 * lane] = acc0;
        orow[2 * lane + 1] = acc1;
        orow[16 + 2 * lane] = acc2;
        orow[16 + 2 * lane + 1] = acc3;
    }
}

extern "C" void kernel_launch(void* const* d_in, const int* in_sizes, int n_in,
                              void* d_out, int out_size, void* d_ws, size_t ws_size,
                              hipStream_t stream) {
    const int E = in_sizes[0] / 2;            // edge_index is (2, E) int32
    const int N = in_sizes[1] / EMB_DIM;      // embedding is (N, 128) f32
    const int nbuck = (N + FINE_W - 1) >> FINE_BITS;   // 1563 for N=100000

    const int* edge_index = (const int*)d_in[0];
    const int* row = edge_index;              // sources
    const int* col = edge_index + E;          // destinations
    const float* emb = (const float*)d_in[1];
    float* out = (float*)d_out;

    // slack per bucket: mean + 25% + 1024 (>>10 sigma for random edges),
    // clamped to the K3 LDS sort capacity.
    const int expected = (int)(((long long)E * FINE_W + N - 1) / N);
    int slack = expected + (expected >> 2) + 1024;
    if (slack > MAX_SLACK) slack = MAX_SLACK;
    const size_t bucketEntries = (size_t)nbuck * slack;

    char* ws = (char*)d_ws;
    size_t off = 0;
    auto alloc = [&](size_t bytes) -> void* {
        off = (off + 255) & ~(size_t)255;
        void* p = ws + off;
        off += bytes;
        return p;
    };

    size_t szEmb16 = (size_t)N * EMB_DIM * 2;
    size_t needCommon = (size_t)MAXB * 4 + (size_t)N * 8 +
                        bucketEntries * 4 + 16 * 256;
    bool useFp16 = (needCommon + szEmb16) <= ws_size;

    int*            colCur    = (int*)alloc((size_t)MAXB * 4);  // adjacent to deg
    int*            deg       = (int*)alloc((size_t)N * 4);
    float*          dis       = (float*)alloc((size_t)N * 4);
    unsigned int*   colBucket = (unsigned int*)alloc(bucketEntries * 4);
    __half*         emb16     = useFp16 ? (__half*)alloc(szEmb16) : (__half*)nullptr;

    const int nchunks = (E + CHUNK - 1) / CHUNK;
    const int histB = (E + SB * HIST_EPT - 1) / (SB * HIST_EPT);
    long long n8 = useFp16 ? (long long)N * EMB_DIM / 8 : 0;
    int cvtBlocks = useFp16 ? (int)((n8 + SB - 1) / SB) : 0;

    // zero relative cursors + degree histogram (adjacent; MAXB*4 is
    // 256-aligned so deg starts exactly at colCur + MAXB)
    hipMemsetAsync(colCur, 0, (size_t)MAXB * 4 + (size_t)N * 4, stream);

    scatter_cvt_kernel<<<nchunks + histB + cvtBlocks, SB, 0, stream>>>(
        row, col, colCur, deg, colBucket, emb, emb16, n8, slack, nchunks, histB, E);

    dis_kernel<<<(N + 255) / 256, 256, 0, stream>>>(deg, dis, N);

    if (useFp16) {
        gather_kernel<true><<<nbuck, 512, 0, stream>>>(
            emb16, emb, dis, colBucket, colCur, out, slack, N);
    } else {
        gather_kernel<false><<<nbuck, 512, 0, stream>>>(
            nullptr, emb, dis, colBucket, colCur, out, slack, N);
    }
}

// Round 9
// 211.724 us; speedup vs baseline: 1.1667x; 1.1667x over previous
//
#include <hip/hip_runtime.h>
#include <hip/hip_fp16.h>
#include <math.h>

#define EMB_DIM 128
#define FINE_BITS 6
#define FINE_W 64           // nodes per dest bucket (= one K3 block)
#define MAXB 2048           // max coarse buckets (N <= 131072)
#define CHUNK 4096          // edges per scatter block (proven tail-parallel point)
#define MAX_SLACK 4096      // LDS sorted capacity (slack clamped to this)
#define SB 512              // scatter block threads

// ---------------------------------------------------------------------------
// K1 (fused): blocks [0,nchunks): col-side coarse scatter; [nchunks,2*nchunks):
// row-side coarse scatter; [2*nchunks, ...): f32->fp16 embedding convert.
// Cursors are RELATIVE (zeroed by memset); absolute base = bucket*slack.
// NOTE (r1, r8): deg via global atomicAdd measured 2x WORSE than this
// sort-side path, both interleaved and batched — coherent-point RMW
// throughput, not vmcnt ordering. Do not revisit.
__global__ __launch_bounds__(SB) void scatter_cvt_kernel(
    const int* __restrict__ row, const int* __restrict__ col,
    int* __restrict__ colCur, int* __restrict__ rowCur,
    unsigned int* __restrict__ colBucket, unsigned char* __restrict__ rowBucket,
    const float* __restrict__ emb, __half* __restrict__ emb16, long long n8,
    int slack, int nchunks, int e) {
    int bid = blockIdx.x;
    int tid = threadIdx.x;
    if (bid >= 2 * nchunks) {
        // ---- cvt tail: 8 floats -> 8 halves per thread ----
        long long t = (long long)(bid - 2 * nchunks) * SB + tid;
        if (t < n8) {
            const float4* src = (const float4*)(emb) + t * 2;
            float4 a = src[0];
            float4 b = src[1];
            __half h[8];
            h[0] = __float2half(a.x); h[1] = __float2half(a.y);
            h[2] = __float2half(a.z); h[3] = __float2half(a.w);
            h[4] = __float2half(b.x); h[5] = __float2half(b.y);
            h[6] = __float2half(b.z); h[7] = __float2half(b.w);
            ((uint4*)emb16)[t] = *(const uint4*)h;
        }
        return;
    }
    __shared__ int lh[MAXB], lb[MAXB];
    bool doRow = bid >= nchunks;
    int chunk = doRow ? bid - nchunks : bid;
    int base = chunk * CHUNK;
    int lim = min(base + CHUNK, e);
    int nfull4 = (lim - base) >> 2;            // # of full int4 groups

    for (int t = tid; t < MAXB; t += SB) lh[t] = 0;
    __syncthreads();
    if (!doRow) {
        for (int g = tid; g < nfull4; g += SB) {
            int4 c4 = *(const int4*)(col + base + 4 * g);
            atomicAdd(&lh[c4.x >> FINE_BITS], 1);
            atomicAdd(&lh[c4.y >> FINE_BITS], 1);
            atomicAdd(&lh[c4.z >> FINE_BITS], 1);
            atomicAdd(&lh[c4.w >> FINE_BITS], 1);
        }
        for (int i = base + 4 * nfull4 + tid; i < lim; i += SB)
            atomicAdd(&lh[col[i] >> FINE_BITS], 1);
        __syncthreads();
        for (int t = tid; t < MAXB; t += SB)
            lb[t] = lh[t] ? (t * slack + atomicAdd(&colCur[t], lh[t])) : 0;
        __syncthreads();
        for (int t = tid; t < MAXB; t += SB) lh[t] = 0;
        __syncthreads();
        for (int g = tid; g < nfull4; g += SB) {
            int4 c4 = *(const int4*)(col + base + 4 * g);
            int4 r4 = *(const int4*)(row + base + 4 * g);
            #pragma unroll
            for (int k = 0; k < 4; ++k) {
                int c = (&c4.x)[k], r = (&r4.x)[k];
                int cb = c >> FINE_BITS;
                int p = lb[cb] + atomicAdd(&lh[cb], 1);
                if (p < (cb + 1) * slack)
                    colBucket[p] = ((unsigned)r << FINE_BITS) | (unsigned)(c & (FINE_W - 1));
            }
        }
        for (int i = base + 4 * nfull4 + tid; i < lim; i += SB) {
            int c = col[i], r = row[i];
            int cb = c >> FINE_BITS;
            int p = lb[cb] + atomicAdd(&lh[cb], 1);
            if (p < (cb + 1) * slack)
                colBucket[p] = ((unsigned)r << FINE_BITS) | (unsigned)(c & (FINE_W - 1));
        }
    } else {
        for (int g = tid; g < nfull4; g += SB) {
            int4 r4 = *(const int4*)(row + base + 4 * g);
            atomicAdd(&lh[r4.x >> FINE_BITS], 1);
            atomicAdd(&lh[r4.y >> FINE_BITS], 1);
            atomicAdd(&lh[r4.z >> FINE_BITS], 1);
            atomicAdd(&lh[r4.w >> FINE_BITS], 1);
        }
        for (int i = base + 4 * nfull4 + tid; i < lim; i += SB)
            atomicAdd(&lh[row[i] >> FINE_BITS], 1);
        __syncthreads();
        for (int t = tid; t < MAXB; t += SB)
            lb[t] = lh[t] ? (t * slack + atomicAdd(&rowCur[t], lh[t])) : 0;
        __syncthreads();
        for (int t = tid; t < MAXB; t += SB) lh[t] = 0;
        __syncthreads();
        for (int g = tid; g < nfull4; g += SB) {
            int4 r4 = *(const int4*)(row + base + 4 * g);
            #pragma unroll
            for (int k = 0; k < 4; ++k) {
                int r = (&r4.x)[k];
                int rb = r >> FINE_BITS;
                int q = lb[rb] + atomicAdd(&lh[rb], 1);
                if (q < (rb + 1) * slack)
                    rowBucket[q] = (unsigned char)(r & (FINE_W - 1));
            }
        }
        for (int i = base + 4 * nfull4 + tid; i < lim; i += SB) {
            int r = row[i];
            int rb = r >> FINE_BITS;
            int q = lb[rb] + atomicAdd(&lh[rb], 1);
            if (q < (rb + 1) * slack)
                rowBucket[q] = (unsigned char)(r & (FINE_W - 1));
        }
    }
}

// ---------------------------------------------------------------------------
// K2: row-side fine histogram -> dis = rsqrt(1+deg). One block per bucket.
__global__ __launch_bounds__(256) void deg_kernel(
    const unsigned char* __restrict__ rowBucket, const int* __restrict__ rowCurF,
    float* __restrict__ dis, int slack, int n) {
    __shared__ int fh[FINE_W];
    int b = blockIdx.x;
    unsigned t = threadIdx.x;
    int start = b * slack;
    int end = start + min(rowCurF[b], slack);
    if (t < FINE_W) fh[t] = 0;
    __syncthreads();
    for (int i = start + (int)t; i < end; i += 256)
        atomicAdd(&fh[rowBucket[i]], 1);
    __syncthreads();
    if (t < FINE_W) {
        int node = (b << FINE_BITS) + (int)t;
        if (node < n) dis[node] = rsqrtf(1.0f + (float)fh[t]);
    }
}

// ---------------------------------------------------------------------------
// K3: bucket gather, register accumulation. One 512-thread block per
// 64-node bucket:
//   phase 1: in-block counting sort by fine node; the scatter pass ALSO
//            prefetches dis[src] (512 thr x ~2 loads, high MLP) and packs
//            {src, dis} as float2 -> one ds_read_b64 in phase 2 removes the
//            serial random 4B global load from the per-edge critical path.
//   phase 2: 64 groups x 8 lanes; group g accumulates node g's contiguous
//            edge range in registers, unroll-2 (proven shape, VGPR 32).
// Self-loop folded into accumulator init (norm = dc^2).
template <bool FP16>
__global__ __launch_bounds__(512) void gather_kernel(
    const __half* __restrict__ emb16, const float* __restrict__ emb,
    const float* __restrict__ dis, const unsigned int* __restrict__ colBucket,
    const int* __restrict__ colCurF, float* __restrict__ out,
    int slack, int n) {
    __shared__ int binCnt[FINE_W];
    __shared__ int binStart[FINE_W];
    __shared__ int binCur[FINE_W];
    __shared__ float2 sorted[MAX_SLACK];   // {src_as_float, dis[src]}
    __shared__ float disl[FINE_W];
    int b = blockIdx.x;
    int tid = threadIdx.x;
    int nodeBase = b << FINE_BITS;
    int start = b * slack;
    int cnt = min(colCurF[b], slack);

    if (tid < FINE_W) {
        binCnt[tid] = 0;
        int node = nodeBase + tid;
        disl[tid] = (node < n) ? dis[node] : 0.0f;
    }
    __syncthreads();

    // ---- phase 1a: fine histogram (coalesced global read, int LDS atomics)
    for (int i = tid; i < cnt; i += 512)
        atomicAdd(&binCnt[colBucket[start + i] & (FINE_W - 1)], 1);
    __syncthreads();

    // ---- phase 1b: exclusive scan of 64 bins entirely inside wave 0
    if (tid < FINE_W) {
        int v = binCnt[tid];
        int incl = v;
        #pragma unroll
        for (int d = 1; d < FINE_W; d <<= 1) {
            int u = __shfl_up(incl, d, FINE_W);
            if (tid >= d) incl += u;
        }
        binStart[tid] = incl - v;
        binCur[tid] = incl - v;
    }
    __syncthreads();

    // ---- phase 1c: scatter {src, dis[src]} into node-contiguous LDS order
    for (int i = tid; i < cnt; i += 512) {
        unsigned v = colBucket[start + i];
        int r = (int)(v >> FINE_BITS);
        float d = dis[r];                       // random 4B, high-MLP here
        int p = atomicAdd(&binCur[v & (FINE_W - 1)], 1);
        sorted[p] = make_float2(__int_as_float(r), d);
    }
    __syncthreads();

    // ---- phase 2: register accumulation, 8 lanes per node, 16 dims/lane
    int g = tid >> 3;        // node within bucket
    int lane = tid & 7;
    int node = nodeBase + g;
    int node_s = (node < n) ? node : 0;
    float dc = disl[g];
    float s = dc * dc;
    float4 acc0, acc1, acc2, acc3;

#define ACCUM_FP16(SRC, NRM)                                                    \
    {                                                                           \
        const uint4* hrow = (const uint4*)(emb16 + (long long)(SRC) * EMB_DIM); \
        uint4 ha = hrow[lane];                                                  \
        uint4 hb = hrow[lane + 8];                                              \
        const __half2* pa = (const __half2*)&ha;                                \
        const __half2* pb = (const __half2*)&hb;                                \
        float2 f0 = __half22float2(pa[0]), f1 = __half22float2(pa[1]);          \
        float2 f2 = __half22float2(pa[2]), f3 = __half22float2(pa[3]);          \
        float2 g0 = __half22float2(pb[0]), g1 = __half22float2(pb[1]);          \
        float2 g2 = __half22float2(pb[2]), g3 = __half22float2(pb[3]);          \
        acc0.x += (NRM) * f0.x; acc0.y += (NRM) * f0.y;                         \
        acc0.z += (NRM) * f1.x; acc0.w += (NRM) * f1.y;                         \
        acc1.x += (NRM) * f2.x; acc1.y += (NRM) * f2.y;                         \
        acc1.z += (NRM) * f3.x; acc1.w += (NRM) * f3.y;                         \
        acc2.x += (NRM) * g0.x; acc2.y += (NRM) * g0.y;                         \
        acc2.z += (NRM) * g1.x; acc2.w += (NRM) * g1.y;                         \
        acc3.x += (NRM) * g2.x; acc3.y += (NRM) * g2.y;                         \
        acc3.z += (NRM) * g3.x; acc3.w += (NRM) * g3.y;                         \
    }

#define ACCUM_FP32(SRC, NRM)                                                    \
    {                                                                           \
        const float4* frow = (const float4*)(emb + (long long)(SRC) * EMB_DIM); \
        float4 v0 = frow[2 * lane];                                             \
        float4 v1 = frow[2 * lane + 1];                                         \
        float4 v2 = frow[16 + 2 * lane];                                        \
        float4 v3 = frow[16 + 2 * lane + 1];                                    \
        acc0.x += (NRM) * v0.x; acc0.y += (NRM) * v0.y;                         \
        acc0.z += (NRM) * v0.z; acc0.w += (NRM) * v0.w;                         \
        acc1.x += (NRM) * v1.x; acc1.y += (NRM) * v1.y;                         \
        acc1.z += (NRM) * v1.z; acc1.w += (NRM) * v1.w;                         \
        acc2.x += (NRM) * v2.x; acc2.y += (NRM) * v2.y;                         \
        acc2.z += (NRM) * v2.z; acc2.w += (NRM) * v2.w;                         \
        acc3.x += (NRM) * v3.x; acc3.y += (NRM) * v3.y;                         \
        acc3.z += (NRM) * v3.z; acc3.w += (NRM) * v3.w;                         \
    }

    // self-loop init: acc = dis^2 * emb[node] (s==0 for padding rows)
    acc0 = acc1 = acc2 = acc3 = float4{0, 0, 0, 0};
    if (FP16) { ACCUM_FP16(node_s, s); } else { ACCUM_FP32(node_s, s); }

    int i = binStart[g];
    int end = i + binCnt[g];
    for (; i + 2 <= end; i += 2) {
        float2 e0 = sorted[i], e1 = sorted[i + 1];
        int s0 = __float_as_int(e0.x), s1 = __float_as_int(e1.x);
        float n0 = dc * e0.y;
        float n1 = dc * e1.y;
        if (FP16) { ACCUM_FP16(s0, n0); ACCUM_FP16(s1, n1); }
        else      { ACCUM_FP32(s0, n0); ACCUM_FP32(s1, n1); }
    }
    if (i < end) {
        float2 e0 = sorted[i];
        int s0 = __float_as_int(e0.x);
        float n0 = dc * e0.y;
        if (FP16) { ACCUM_FP16(s0, n0); } else { ACCUM_FP32(s0, n0); }
    }
#undef ACCUM_FP16
#undef ACCUM_FP32

    if (node < n) {
        float4* orow = (float4*)(out + (long long)node * EMB_DIM);
        orow[2 * lane] = acc0;
        orow[2 * lane + 1] = acc1;
        orow[16 + 2 * lane] = acc2;
        orow[16 + 2 * lane + 1] = acc3;
    }
}

extern "C" void kernel_launch(void* const* d_in, const int* in_sizes, int n_in,
                              void* d_out, int out_size, void* d_ws, size_t ws_size,
                              hipStream_t stream) {
    const int E = in_sizes[0] / 2;            // edge_index is (2, E) int32
    const int N = in_sizes[1] / EMB_DIM;      // embedding is (N, 128) f32
    const int nbuck = (N + FINE_W - 1) >> FINE_BITS;   // 1563 for N=100000

    const int* edge_index = (const int*)d_in[0];
    const int* row = edge_index;              // sources
    const int* col = edge_index + E;          // destinations
    const float* emb = (const float*)d_in[1];
    float* out = (float*)d_out;

    // slack per bucket: mean + 25% + 1024 (>>10 sigma for random edges),
    // clamped to the K3 LDS sort capacity.
    const int expected = (int)(((long long)E * FINE_W + N - 1) / N);
    int slack = expected + (expected >> 2) + 1024;
    if (slack > MAX_SLACK) slack = MAX_SLACK;
    const size_t bucketEntries = (size_t)nbuck * slack;

    char* ws = (char*)d_ws;
    size_t off = 0;
    auto alloc = [&](size_t bytes) -> void* {
        off = (off + 255) & ~(size_t)255;
        void* p = ws + off;
        off += bytes;
        return p;
    };

    size_t szEmb16 = (size_t)N * EMB_DIM * 2;
    size_t needCommon = (size_t)MAXB * 8 + (size_t)N * 4 +
                        bucketEntries * 5 + 16 * 256;
    bool useFp16 = (needCommon + szEmb16) <= ws_size;

    int*            colCur    = (int*)alloc((size_t)MAXB * 4);
    int*            rowCur    = (int*)alloc((size_t)MAXB * 4);   // adjacent to colCur
    float*          dis       = (float*)alloc((size_t)N * 4);
    unsigned int*   colBucket = (unsigned int*)alloc(bucketEntries * 4);
    unsigned char*  rowBucket = (unsigned char*)alloc(bucketEntries);
    __half*         emb16     = useFp16 ? (__half*)alloc(szEmb16) : (__half*)nullptr;

    const int nchunks = (E + CHUNK - 1) / CHUNK;
    long long n8 = useFp16 ? (long long)N * EMB_DIM / 8 : 0;
    int cvtBlocks = useFp16 ? (int)((n8 + SB - 1) / SB) : 0;

    // zero both relative cursor arrays (adjacent, MAXB*4 each, 256-aligned)
    hipMemsetAsync(colCur, 0, (size_t)MAXB * 8, stream);

    scatter_cvt_kernel<<<2 * nchunks + cvtBlocks, SB, 0, stream>>>(
        row, col, colCur, rowCur, colBucket, rowBucket,
        emb, emb16, n8, slack, nchunks, E);

    deg_kernel<<<nbuck, 256, 0, stream>>>(rowBucket, rowCur, dis, slack, N);

    if (useFp16) {
        gather_kernel<true><<<nbuck, 512, 0, stream>>>(
            emb16, emb, dis, colBucket, colCur, out, slack, N);
    } else {
        gather_kernel<false><<<nbuck, 512, 0, stream>>>(
            nullptr, emb, dis, colBucket, colCur, out, slack, N);
    }
}

// Round 10
// 206.092 us; speedup vs baseline: 1.1986x; 1.0273x over previous
//
#include <hip/hip_runtime.h>
#include <hip/hip_fp16.h>
#include <math.h>

#define EMB_DIM 128
#define FINE_BITS 6
#define FINE_W 64           // nodes per dest bucket (= one K3 block)
#define MAXB 2048           // max coarse buckets (N <= 131072)
#define CHUNK 4096          // edges per scatter block (proven tail-parallel point)
#define MAX_SLACK 4096      // LDS sorted capacity (slack clamped to this)
#define SB 512              // scatter block threads
#define EPT (CHUNK / SB)    // 8 edges per thread in a full chunk

// ---------------------------------------------------------------------------
// K1 (fused): blocks [0,nchunks): MERGED row+col coarse scatter — edges are
// loaded into registers ONCE, histogrammed for both sides, cursors for both
// sides reserved in the same loop (two independent global atomics -> their
// ~700cy latencies overlap), then placed from registers via atomicAdd
// directly on the absolute cursor array (no re-zero pass, one less barrier).
// Blocks [nchunks, ...): f32->fp16 embedding convert (BW-bound filler).
// NOTE (r1, r8): per-edge deg via global atomicAdd measured 2x WORSE than
// this sort-side path (coherent-point RMW throughput). Do not revisit.
__global__ __launch_bounds__(SB) void scatter_cvt_kernel(
    const int* __restrict__ row, const int* __restrict__ col,
    int* __restrict__ colCur, int* __restrict__ rowCur,
    unsigned int* __restrict__ colBucket, unsigned char* __restrict__ rowBucket,
    const float* __restrict__ emb, __half* __restrict__ emb16, long long n8,
    int slack, int nchunks, int e) {
    int bid = blockIdx.x;
    int tid = threadIdx.x;
    if (bid >= nchunks) {
        // ---- cvt tail: 8 floats -> 8 halves per thread ----
        long long t = (long long)(bid - nchunks) * SB + tid;
        if (t < n8) {
            const float4* src = (const float4*)(emb) + t * 2;
            float4 a = src[0];
            float4 b = src[1];
            __half h[8];
            h[0] = __float2half(a.x); h[1] = __float2half(a.y);
            h[2] = __float2half(a.z); h[3] = __float2half(a.w);
            h[4] = __float2half(b.x); h[5] = __float2half(b.y);
            h[6] = __float2half(b.z); h[7] = __float2half(b.w);
            ((uint4*)emb16)[t] = *(const uint4*)h;
        }
        return;
    }
    __shared__ int ch[MAXB], cc[MAXB];   // col hist / col absolute cursor
    __shared__ int rh[MAXB], rc[MAXB];   // row hist / row absolute cursor
    int base = bid * CHUNK;
    int lim = min(base + CHUNK, e);

    for (int t = tid; t < MAXB; t += SB) { ch[t] = 0; rh[t] = 0; }
    __syncthreads();

#define PLACE(C, R)                                                             \
    {                                                                           \
        int cb2 = (C) >> FINE_BITS;                                             \
        int p = atomicAdd(&cc[cb2], 1);                                         \
        if (p < (cb2 + 1) * slack)                                              \
            colBucket[p] = ((unsigned)(R) << FINE_BITS) |                       \
                           ((unsigned)(C) & (FINE_W - 1));                      \
        int rb2 = (R) >> FINE_BITS;                                             \
        int q = atomicAdd(&rc[rb2], 1);                                         \
        if (q < (rb2 + 1) * slack)                                              \
            rowBucket[q] = (unsigned char)((R) & (FINE_W - 1));                 \
    }

    if (lim - base == CHUNK) {
        // ---- full chunk: register-cached edges (2x int4 per side/thread) ----
        const int4* cp = (const int4*)(col + base);
        const int4* rp = (const int4*)(row + base);
        int4 c0 = cp[tid], c1 = cp[tid + SB];
        int4 r0 = rp[tid], r1 = rp[tid + SB];
        atomicAdd(&ch[c0.x >> FINE_BITS], 1); atomicAdd(&ch[c0.y >> FINE_BITS], 1);
        atomicAdd(&ch[c0.z >> FINE_BITS], 1); atomicAdd(&ch[c0.w >> FINE_BITS], 1);
        atomicAdd(&ch[c1.x >> FINE_BITS], 1); atomicAdd(&ch[c1.y >> FINE_BITS], 1);
        atomicAdd(&ch[c1.z >> FINE_BITS], 1); atomicAdd(&ch[c1.w >> FINE_BITS], 1);
        atomicAdd(&rh[r0.x >> FINE_BITS], 1); atomicAdd(&rh[r0.y >> FINE_BITS], 1);
        atomicAdd(&rh[r0.z >> FINE_BITS], 1); atomicAdd(&rh[r0.w >> FINE_BITS], 1);
        atomicAdd(&rh[r1.x >> FINE_BITS], 1); atomicAdd(&rh[r1.y >> FINE_BITS], 1);
        atomicAdd(&rh[r1.z >> FINE_BITS], 1); atomicAdd(&rh[r1.w >> FINE_BITS], 1);
        __syncthreads();
        for (int t = tid; t < MAXB; t += SB) {
            int hc = ch[t], hr = rh[t];
            cc[t] = hc ? (t * slack + atomicAdd(&colCur[t], hc)) : 0;
            rc[t] = hr ? (t * slack + atomicAdd(&rowCur[t], hr)) : 0;
        }
        __syncthreads();
        PLACE(c0.x, r0.x) PLACE(c0.y, r0.y) PLACE(c0.z, r0.z) PLACE(c0.w, r0.w)
        PLACE(c1.x, r1.x) PLACE(c1.y, r1.y) PLACE(c1.z, r1.z) PLACE(c1.w, r1.w)
    } else {
        // ---- tail chunk (at most 1 block): simple scalar two-pass ----
        for (int i = base + tid; i < lim; i += SB) {
            atomicAdd(&ch[col[i] >> FINE_BITS], 1);
            atomicAdd(&rh[row[i] >> FINE_BITS], 1);
        }
        __syncthreads();
        for (int t = tid; t < MAXB; t += SB) {
            int hc = ch[t], hr = rh[t];
            cc[t] = hc ? (t * slack + atomicAdd(&colCur[t], hc)) : 0;
            rc[t] = hr ? (t * slack + atomicAdd(&rowCur[t], hr)) : 0;
        }
        __syncthreads();
        for (int i = base + tid; i < lim; i += SB) {
            int c = col[i], r = row[i];
            PLACE(c, r)
        }
    }
#undef PLACE
}

// ---------------------------------------------------------------------------
// K2: row-side fine histogram -> dis = rsqrt(1+deg). One block per bucket.
__global__ __launch_bounds__(256) void deg_kernel(
    const unsigned char* __restrict__ rowBucket, const int* __restrict__ rowCurF,
    float* __restrict__ dis, int slack, int n) {
    __shared__ int fh[FINE_W];
    int b = blockIdx.x;
    unsigned t = threadIdx.x;
    int start = b * slack;
    int end = start + min(rowCurF[b], slack);
    if (t < FINE_W) fh[t] = 0;
    __syncthreads();
    for (int i = start + (int)t; i < end; i += 256)
        atomicAdd(&fh[rowBucket[i]], 1);
    __syncthreads();
    if (t < FINE_W) {
        int node = (b << FINE_BITS) + (int)t;
        if (node < n) dis[node] = rsqrtf(1.0f + (float)fh[t]);
    }
}

// ---------------------------------------------------------------------------
// K3: bucket gather, register accumulation (r7 proven exactly: 68.5us,
// VGPR 32 — r9's dis-prefetch variant measured WORSE, reverted).
// One 512-thread block per 64-node bucket:
//   phase 1: in-block counting sort of the bucket's ~1K edges by fine node;
//   phase 2: 64 groups x 8 lanes; group g accumulates node g's contiguous
//            edge range in registers, unroll-2. Self-loop in init (norm=dc^2).
// Gather is at the random-row L3-fetch ceiling: 2.8-2.9 TB/s L2-miss traffic
// across 4 structurally different implementations (r0/r5/r7/r9).
template <bool FP16>
__global__ __launch_bounds__(512) void gather_kernel(
    const __half* __restrict__ emb16, const float* __restrict__ emb,
    const float* __restrict__ dis, const unsigned int* __restrict__ colBucket,
    const int* __restrict__ colCurF, float* __restrict__ out,
    int slack, int n) {
    __shared__ int binCnt[FINE_W];
    __shared__ int binStart[FINE_W];
    __shared__ int binCur[FINE_W];
    __shared__ int sortedR[MAX_SLACK];
    __shared__ float disl[FINE_W];
    int b = blockIdx.x;
    int tid = threadIdx.x;
    int nodeBase = b << FINE_BITS;
    int start = b * slack;
    int cnt = min(colCurF[b], slack);

    if (tid < FINE_W) {
        binCnt[tid] = 0;
        int node = nodeBase + tid;
        disl[tid] = (node < n) ? dis[node] : 0.0f;
    }
    __syncthreads();

    // ---- phase 1a: fine histogram (coalesced global read, int LDS atomics)
    for (int i = tid; i < cnt; i += 512)
        atomicAdd(&binCnt[colBucket[start + i] & (FINE_W - 1)], 1);
    __syncthreads();

    // ---- phase 1b: exclusive scan of 64 bins entirely inside wave 0
    if (tid < FINE_W) {
        int v = binCnt[tid];
        int incl = v;
        #pragma unroll
        for (int d = 1; d < FINE_W; d <<= 1) {
            int u = __shfl_up(incl, d, FINE_W);
            if (tid >= d) incl += u;
        }
        binStart[tid] = incl - v;
        binCur[tid] = incl - v;
    }
    __syncthreads();

    // ---- phase 1c: scatter source ids into node-contiguous LDS order
    for (int i = tid; i < cnt; i += 512) {
        unsigned v = colBucket[start + i];
        int p = atomicAdd(&binCur[v & (FINE_W - 1)], 1);
        sortedR[p] = (int)(v >> FINE_BITS);
    }
    __syncthreads();

    // ---- phase 2: register accumulation, 8 lanes per node, 16 dims/lane
    int g = tid >> 3;        // node within bucket
    int lane = tid & 7;
    int node = nodeBase + g;
    int node_s = (node < n) ? node : 0;
    float dc = disl[g];
    float s = dc * dc;
    float4 acc0, acc1, acc2, acc3;

#define ACCUM_FP16(SRC, NRM)                                                    \
    {                                                                           \
        const uint4* hrow = (const uint4*)(emb16 + (long long)(SRC) * EMB_DIM); \
        uint4 ha = hrow[lane];                                                  \
        uint4 hb = hrow[lane + 8];                                              \
        const __half2* pa = (const __half2*)&ha;                                \
        const __half2* pb = (const __half2*)&hb;                                \
        float2 f0 = __half22float2(pa[0]), f1 = __half22float2(pa[1]);          \
        float2 f2 = __half22float2(pa[2]), f3 = __half22float2(pa[3]);          \
        float2 g0 = __half22float2(pb[0]), g1 = __half22float2(pb[1]);          \
        float2 g2 = __half22float2(pb[2]), g3 = __half22float2(pb[3]);          \
        acc0.x += (NRM) * f0.x; acc0.y += (NRM) * f0.y;                         \
        acc0.z += (NRM) * f1.x; acc0.w += (NRM) * f1.y;                         \
        acc1.x += (NRM) * f2.x; acc1.y += (NRM) * f2.y;                         \
        acc1.z += (NRM) * f3.x; acc1.w += (NRM) * f3.y;                         \
        acc2.x += (NRM) * g0.x; acc2.y += (NRM) * g0.y;                         \
        acc2.z += (NRM) * g1.x; acc2.w += (NRM) * g1.y;                         \
        acc3.x += (NRM) * g2.x; acc3.y += (NRM) * g2.y;                         \
        acc3.z += (NRM) * g3.x; acc3.w += (NRM) * g3.y;                         \
    }

#define ACCUM_FP32(SRC, NRM)                                                    \
    {                                                                           \
        const float4* frow = (const float4*)(emb + (long long)(SRC) * EMB_DIM); \
        float4 v0 = frow[2 * lane];                                             \
        float4 v1 = frow[2 * lane + 1];                                         \
        float4 v2 = frow[16 + 2 * lane];                                        \
        float4 v3 = frow[16 + 2 * lane + 1];                                    \
        acc0.x += (NRM) * v0.x; acc0.y += (NRM) * v0.y;                         \
        acc0.z += (NRM) * v0.z; acc0.w += (NRM) * v0.w;                         \
        acc1.x += (NRM) * v1.x; acc1.y += (NRM) * v1.y;                         \
        acc1.z += (NRM) * v1.z; acc1.w += (NRM) * v1.w;                         \
        acc2.x += (NRM) * v2.x; acc2.y += (NRM) * v2.y;                         \
        acc2.z += (NRM) * v2.z; acc2.w += (NRM) * v2.w;                         \
        acc3.x += (NRM) * v3.x; acc3.y += (NRM) * v3.y;                         \
        acc3.z += (NRM) * v3.z; acc3.w += (NRM) * v3.w;                         \
    }

    // self-loop init: acc = dis^2 * emb[node] (s==0 for padding rows)
    acc0 = acc1 = acc2 = acc3 = float4{0, 0, 0, 0};
    if (FP16) { ACCUM_FP16(node_s, s); } else { ACCUM_FP32(node_s, s); }

    int i = binStart[g];
    int end = i + binCnt[g];
    for (; i + 2 <= end; i += 2) {
        int s0 = sortedR[i], s1 = sortedR[i + 1];
        float n0 = dc * dis[s0];
        float n1 = dc * dis[s1];
        if (FP16) { ACCUM_FP16(s0, n0); ACCUM_FP16(s1, n1); }
        else      { ACCUM_FP32(s0, n0); ACCUM_FP32(s1, n1); }
    }
    if (i < end) {
        int s0 = sortedR[i];
        float n0 = dc * dis[s0];
        if (FP16) { ACCUM_FP16(s0, n0); } else { ACCUM_FP32(s0, n0); }
    }
#undef ACCUM_FP16
#undef ACCUM_FP32

    if (node < n) {
        float4* orow = (float4*)(out + (long long)node * EMB_DIM);
        orow[2 * lane] = acc0;
        orow[2 * lane + 1] = acc1;
        orow[16 + 2 * lane] = acc2;
        orow[16 + 2 * lane + 1] = acc3;
    }
}

extern "C" void kernel_launch(void* const* d_in, const int* in_sizes, int n_in,
                              void* d_out, int out_size, void* d_ws, size_t ws_size,
                              hipStream_t stream) {
    const int E = in_sizes[0] / 2;            // edge_index is (2, E) int32
    const int N = in_sizes[1] / EMB_DIM;      // embedding is (N, 128) f32
    const int nbuck = (N + FINE_W - 1) >> FINE_BITS;   // 1563 for N=100000

    const int* edge_index = (const int*)d_in[0];
    const int* row = edge_index;              // sources
    const int* col = edge_index + E;          // destinations
    const float* emb = (const float*)d_in[1];
    float* out = (float*)d_out;

    // slack per bucket: mean + 25% + 1024 (>>10 sigma for random edges),
    // clamped to the K3 LDS sort capacity.
    const int expected = (int)(((long long)E * FINE_W + N - 1) / N);
    int slack = expected + (expected >> 2) + 1024;
    if (slack > MAX_SLACK) slack = MAX_SLACK;
    const size_t bucketEntries = (size_t)nbuck * slack;

    char* ws = (char*)d_ws;
    size_t off = 0;
    auto alloc = [&](size_t bytes) -> void* {
        off = (off + 255) & ~(size_t)255;
        void* p = ws + off;
        off += bytes;
        return p;
    };

    size_t szEmb16 = (size_t)N * EMB_DIM * 2;
    size_t needCommon = (size_t)MAXB * 8 + (size_t)N * 4 +
                        bucketEntries * 5 + 16 * 256;
    bool useFp16 = (needCommon + szEmb16) <= ws_size;

    int*            colCur    = (int*)alloc((size_t)MAXB * 4);
    int*            rowCur    = (int*)alloc((size_t)MAXB * 4);   // adjacent to colCur
    float*          dis       = (float*)alloc((size_t)N * 4);
    unsigned int*   colBucket = (unsigned int*)alloc(bucketEntries * 4);
    unsigned char*  rowBucket = (unsigned char*)alloc(bucketEntries);
    __half*         emb16     = useFp16 ? (__half*)alloc(szEmb16) : (__half*)nullptr;

    const int nchunks = (E + CHUNK - 1) / CHUNK;
    long long n8 = useFp16 ? (long long)N * EMB_DIM / 8 : 0;
    int cvtBlocks = useFp16 ? (int)((n8 + SB - 1) / SB) : 0;

    // zero both relative cursor arrays (adjacent, MAXB*4 each, 256-aligned)
    hipMemsetAsync(colCur, 0, (size_t)MAXB * 8, stream);

    scatter_cvt_kernel<<<nchunks + cvtBlocks, SB, 0, stream>>>(
        row, col, colCur, rowCur, colBucket, rowBucket,
        emb, emb16, n8, slack, nchunks, E);

    deg_kernel<<<nbuck, 256, 0, stream>>>(rowBucket, rowCur, dis, slack, N);

    if (useFp16) {
        gather_kernel<true><<<nbuck, 512, 0, stream>>>(
            emb16, emb, dis, colBucket, colCur, out, slack, N);
    } else {
        gather_kernel<false><<<nbuck, 512, 0, stream>>>(
            nullptr, emb, dis, colBucket, colCur, out, slack, N);
    }
}

// Round 11
// 205.400 us; speedup vs baseline: 1.2026x; 1.0034x over previous
//
#include <hip/hip_runtime.h>
#include <hip/hip_fp16.h>
#include <math.h>

#define EMB_DIM 128
#define FINE_BITS 6
#define FINE_W 64           // nodes per dest bucket (= one K3 block)
#define MAXB 2048           // max coarse buckets (N <= 131072)
#define CHUNK 4096          // edges per scatter block (proven tail-parallel point)
#define MAX_SLACK 4096      // LDS sorted capacity (slack clamped to this)
#define SB 512              // scatter block threads
#define GJ 8                // gather: cached colBucket entries per thread (8*512=4096)

// ---------------------------------------------------------------------------
// K1 (fused): blocks [0,nchunks): MERGED row+col coarse scatter (r10 proven,
// byte-identical) — edges loaded into registers ONCE, both-side histograms,
// both cursors reserved in one loop (overlapped global-atomic latencies),
// placement from registers on absolute LDS cursors.
// Blocks [nchunks, ...): f32->fp16 embedding convert (BW-bound filler).
// NOTE (r1, r8): per-edge deg via global atomicAdd measured 2x WORSE
// (coherent-point RMW throughput). NOTE (r6): CHUNK>4096 regresses (tail
// parallelism: 196 blocks can't cover the post-cvt tail).
__global__ __launch_bounds__(SB) void scatter_cvt_kernel(
    const int* __restrict__ row, const int* __restrict__ col,
    int* __restrict__ colCur, int* __restrict__ rowCur,
    unsigned int* __restrict__ colBucket, unsigned char* __restrict__ rowBucket,
    const float* __restrict__ emb, __half* __restrict__ emb16, long long n8,
    int slack, int nchunks, int e) {
    int bid = blockIdx.x;
    int tid = threadIdx.x;
    if (bid >= nchunks) {
        // ---- cvt tail: 8 floats -> 8 halves per thread ----
        long long t = (long long)(bid - nchunks) * SB + tid;
        if (t < n8) {
            const float4* src = (const float4*)(emb) + t * 2;
            float4 a = src[0];
            float4 b = src[1];
            __half h[8];
            h[0] = __float2half(a.x); h[1] = __float2half(a.y);
            h[2] = __float2half(a.z); h[3] = __float2half(a.w);
            h[4] = __float2half(b.x); h[5] = __float2half(b.y);
            h[6] = __float2half(b.z); h[7] = __float2half(b.w);
            ((uint4*)emb16)[t] = *(const uint4*)h;
        }
        return;
    }
    __shared__ int ch[MAXB], cc[MAXB];   // col hist / col absolute cursor
    __shared__ int rh[MAXB], rc[MAXB];   // row hist / row absolute cursor
    int base = bid * CHUNK;
    int lim = min(base + CHUNK, e);

    for (int t = tid; t < MAXB; t += SB) { ch[t] = 0; rh[t] = 0; }
    __syncthreads();

#define PLACE(C, R)                                                             \
    {                                                                           \
        int cb2 = (C) >> FINE_BITS;                                             \
        int p = atomicAdd(&cc[cb2], 1);                                         \
        if (p < (cb2 + 1) * slack)                                              \
            colBucket[p] = ((unsigned)(R) << FINE_BITS) |                       \
                           ((unsigned)(C) & (FINE_W - 1));                      \
        int rb2 = (R) >> FINE_BITS;                                             \
        int q = atomicAdd(&rc[rb2], 1);                                         \
        if (q < (rb2 + 1) * slack)                                              \
            rowBucket[q] = (unsigned char)((R) & (FINE_W - 1));                 \
    }

    if (lim - base == CHUNK) {
        // ---- full chunk: register-cached edges (2x int4 per side/thread) ----
        const int4* cp = (const int4*)(col + base);
        const int4* rp = (const int4*)(row + base);
        int4 c0 = cp[tid], c1 = cp[tid + SB];
        int4 r0 = rp[tid], r1 = rp[tid + SB];
        atomicAdd(&ch[c0.x >> FINE_BITS], 1); atomicAdd(&ch[c0.y >> FINE_BITS], 1);
        atomicAdd(&ch[c0.z >> FINE_BITS], 1); atomicAdd(&ch[c0.w >> FINE_BITS], 1);
        atomicAdd(&ch[c1.x >> FINE_BITS], 1); atomicAdd(&ch[c1.y >> FINE_BITS], 1);
        atomicAdd(&ch[c1.z >> FINE_BITS], 1); atomicAdd(&ch[c1.w >> FINE_BITS], 1);
        atomicAdd(&rh[r0.x >> FINE_BITS], 1); atomicAdd(&rh[r0.y >> FINE_BITS], 1);
        atomicAdd(&rh[r0.z >> FINE_BITS], 1); atomicAdd(&rh[r0.w >> FINE_BITS], 1);
        atomicAdd(&rh[r1.x >> FINE_BITS], 1); atomicAdd(&rh[r1.y >> FINE_BITS], 1);
        atomicAdd(&rh[r1.z >> FINE_BITS], 1); atomicAdd(&rh[r1.w >> FINE_BITS], 1);
        __syncthreads();
        for (int t = tid; t < MAXB; t += SB) {
            int hc = ch[t], hr = rh[t];
            cc[t] = hc ? (t * slack + atomicAdd(&colCur[t], hc)) : 0;
            rc[t] = hr ? (t * slack + atomicAdd(&rowCur[t], hr)) : 0;
        }
        __syncthreads();
        PLACE(c0.x, r0.x) PLACE(c0.y, r0.y) PLACE(c0.z, r0.z) PLACE(c0.w, r0.w)
        PLACE(c1.x, r1.x) PLACE(c1.y, r1.y) PLACE(c1.z, r1.z) PLACE(c1.w, r1.w)
    } else {
        // ---- tail chunk (at most 1 block): simple scalar two-pass ----
        for (int i = base + tid; i < lim; i += SB) {
            atomicAdd(&ch[col[i] >> FINE_BITS], 1);
            atomicAdd(&rh[row[i] >> FINE_BITS], 1);
        }
        __syncthreads();
        for (int t = tid; t < MAXB; t += SB) {
            int hc = ch[t], hr = rh[t];
            cc[t] = hc ? (t * slack + atomicAdd(&colCur[t], hc)) : 0;
            rc[t] = hr ? (t * slack + atomicAdd(&rowCur[t], hr)) : 0;
        }
        __syncthreads();
        for (int i = base + tid; i < lim; i += SB) {
            int c = col[i], r = row[i];
            PLACE(c, r)
        }
    }
#undef PLACE
}

// ---------------------------------------------------------------------------
// K2: row-side fine histogram -> dis = rsqrt(1+deg). One 512-thr block per
// bucket; uint loads = 4 rowBucket entries per issue (G13 — the loop was
// issue-bound on byte loads). Host rounds slack to x4 so start is 4-aligned.
__global__ __launch_bounds__(512) void deg_kernel(
    const unsigned char* __restrict__ rowBucket, const int* __restrict__ rowCurF,
    float* __restrict__ dis, int slack, int n) {
    __shared__ int fh[FINE_W];
    int b = blockIdx.x;
    unsigned t = threadIdx.x;
    int start = b * slack;                      // 4-aligned (slack % 4 == 0)
    int cnt = min(rowCurF[b], slack);
    if (t < FINE_W) fh[t] = 0;
    __syncthreads();
    int n4 = cnt >> 2;
    const unsigned int* rb4 = (const unsigned int*)(rowBucket + start);
    for (int i = (int)t; i < n4; i += 512) {
        unsigned w = rb4[i];
        atomicAdd(&fh[w & 255], 1);
        atomicAdd(&fh[(w >> 8) & 255], 1);
        atomicAdd(&fh[(w >> 16) & 255], 1);
        atomicAdd(&fh[w >> 24], 1);
    }
    for (int i = 4 * n4 + (int)t; i < cnt; i += 512)
        atomicAdd(&fh[rowBucket[start + i]], 1);
    __syncthreads();
    if (t < FINE_W) {
        int node = (b << FINE_BITS) + (int)t;
        if (node < n) dis[node] = rsqrtf(1.0f + (float)fh[t]);
    }
}

// ---------------------------------------------------------------------------
// K3: bucket gather, register accumulation (r7 proven inner loop: VGPR 32;
// r9's dis-prefetch measured WORSE — reverted, do not revisit).
// One 512-thread block per 64-node bucket:
//   phase 1: in-block counting sort; colBucket entries are loaded ONCE into
//            a statically-indexed register array (GJ=8, rule: compile-time
//            indices only -> stays in VGPRs) and replayed for the placement
//            pass — deletes the second global stream.
//   phase 2: 64 groups x 8 lanes; group g accumulates node g's contiguous
//            edge range in registers, unroll-2. Self-loop in init (norm=dc^2).
// Gather is at the random-row L3-fetch ceiling: 2.8-2.9 TB/s L2-miss traffic
// across 4 structurally different implementations (r0/r5/r7/r9).
template <bool FP16>
__global__ __launch_bounds__(512) void gather_kernel(
    const __half* __restrict__ emb16, const float* __restrict__ emb,
    const float* __restrict__ dis, const unsigned int* __restrict__ colBucket,
    const int* __restrict__ colCurF, float* __restrict__ out,
    int slack, int n) {
    __shared__ int binCnt[FINE_W];
    __shared__ int binStart[FINE_W];
    __shared__ int binCur[FINE_W];
    __shared__ int sortedR[MAX_SLACK];
    __shared__ float disl[FINE_W];
    int b = blockIdx.x;
    int tid = threadIdx.x;
    int nodeBase = b << FINE_BITS;
    int start = b * slack;
    int cnt = min(colCurF[b], slack);

    if (tid < FINE_W) {
        binCnt[tid] = 0;
        int node = nodeBase + tid;
        disl[tid] = (node < n) ? dis[node] : 0.0f;
    }
    __syncthreads();

    // ---- phase 1a: load entries once into registers + fine histogram ----
    unsigned ent[GJ];
    #pragma unroll
    for (int j = 0; j < GJ; ++j) {
        int i = tid + j * 512;
        ent[j] = (i < cnt) ? colBucket[start + i] : 0xFFFFFFFFu;
    }
    #pragma unroll
    for (int j = 0; j < GJ; ++j)
        if (ent[j] != 0xFFFFFFFFu)
            atomicAdd(&binCnt[ent[j] & (FINE_W - 1)], 1);
    __syncthreads();

    // ---- phase 1b: exclusive scan of 64 bins entirely inside wave 0
    if (tid < FINE_W) {
        int v = binCnt[tid];
        int incl = v;
        #pragma unroll
        for (int d = 1; d < FINE_W; d <<= 1) {
            int u = __shfl_up(incl, d, FINE_W);
            if (tid >= d) incl += u;
        }
        binStart[tid] = incl - v;
        binCur[tid] = incl - v;
    }
    __syncthreads();

    // ---- phase 1c: scatter source ids from registers into LDS order ----
    #pragma unroll
    for (int j = 0; j < GJ; ++j)
        if (ent[j] != 0xFFFFFFFFu) {
            int p = atomicAdd(&binCur[ent[j] & (FINE_W - 1)], 1);
            sortedR[p] = (int)(ent[j] >> FINE_BITS);
        }
    __syncthreads();

    // ---- phase 2: register accumulation, 8 lanes per node, 16 dims/lane
    int g = tid >> 3;        // node within bucket
    int lane = tid & 7;
    int node = nodeBase + g;
    int node_s = (node < n) ? node : 0;
    float dc = disl[g];
    float s = dc * dc;
    float4 acc0, acc1, acc2, acc3;

#define ACCUM_FP16(SRC, NRM)                                                    \
    {                                                                           \
        const uint4* hrow = (const uint4*)(emb16 + (long long)(SRC) * EMB_DIM); \
        uint4 ha = hrow[lane];                                                  \
        uint4 hb = hrow[lane + 8];                                              \
        const __half2* pa = (const __half2*)&ha;                                \
        const __half2* pb = (const __half2*)&hb;                                \
        float2 f0 = __half22float2(pa[0]), f1 = __half22float2(pa[1]);          \
        float2 f2 = __half22float2(pa[2]), f3 = __half22float2(pa[3]);          \
        float2 g0 = __half22float2(pb[0]), g1 = __half22float2(pb[1]);          \
        float2 g2 = __half22float2(pb[2]), g3 = __half22float2(pb[3]);          \
        acc0.x += (NRM) * f0.x; acc0.y += (NRM) * f0.y;                         \
        acc0.z += (NRM) * f1.x; acc0.w += (NRM) * f1.y;                         \
        acc1.x += (NRM) * f2.x; acc1.y += (NRM) * f2.y;                         \
        acc1.z += (NRM) * f3.x; acc1.w += (NRM) * f3.y;                         \
        acc2.x += (NRM) * g0.x; acc2.y += (NRM) * g0.y;                         \
        acc2.z += (NRM) * g1.x; acc2.w += (NRM) * g1.y;                         \
        acc3.x += (NRM) * g2.x; acc3.y += (NRM) * g2.y;                         \
        acc3.z += (NRM) * g3.x; acc3.w += (NRM) * g3.y;                         \
    }

#define ACCUM_FP32(SRC, NRM)                                                    \
    {                                                                           \
        const float4* frow = (const float4*)(emb + (long long)(SRC) * EMB_DIM); \
        float4 v0 = frow[2 * lane];                                             \
        float4 v1 = frow[2 * lane + 1];                                         \
        float4 v2 = frow[16 + 2 * lane];                                        \
        float4 v3 = frow[16 + 2 * lane + 1];                                    \
        acc0.x += (NRM) * v0.x; acc0.y += (NRM) * v0.y;                         \
        acc0.z += (NRM) * v0.z; acc0.w += (NRM) * v0.w;                         \
        acc1.x += (NRM) * v1.x; acc1.y += (NRM) * v1.y;                         \
        acc1.z += (NRM) * v1.z; acc1.w += (NRM) * v1.w;                         \
        acc2.x += (NRM) * v2.x; acc2.y += (NRM) * v2.y;                         \
        acc2.z += (NRM) * v2.z; acc2.w += (NRM) * v2.w;                         \
        acc3.x += (NRM) * v3.x; acc3.y += (NRM) * v3.y;                         \
        acc3.z += (NRM) * v3.z; acc3.w += (NRM) * v3.w;                         \
    }

    // self-loop init: acc = dis^2 * emb[node] (s==0 for padding rows)
    acc0 = acc1 = acc2 = acc3 = float4{0, 0, 0, 0};
    if (FP16) { ACCUM_FP16(node_s, s); } else { ACCUM_FP32(node_s, s); }

    int i = binStart[g];
    int end = i + binCnt[g];
    for (; i + 2 <= end; i += 2) {
        int s0 = sortedR[i], s1 = sortedR[i + 1];
        float n0 = dc * dis[s0];
        float n1 = dc * dis[s1];
        if (FP16) { ACCUM_FP16(s0, n0); ACCUM_FP16(s1, n1); }
        else      { ACCUM_FP32(s0, n0); ACCUM_FP32(s1, n1); }
    }
    if (i < end) {
        int s0 = sortedR[i];
        float n0 = dc * dis[s0];
        if (FP16) { ACCUM_FP16(s0, n0); } else { ACCUM_FP32(s0, n0); }
    }
#undef ACCUM_FP16
#undef ACCUM_FP32

    if (node < n) {
        float4* orow = (float4*)(out + (long long)node * EMB_DIM);
        orow[2 * lane] = acc0;
        orow[2 * lane + 1] = acc1;
        orow[16 + 2 * lane] = acc2;
        orow[16 + 2 * lane + 1] = acc3;
    }
}

extern "C" void kernel_launch(void* const* d_in, const int* in_sizes, int n_in,
                              void* d_out, int out_size, void* d_ws, size_t ws_size,
                              hipStream_t stream) {
    const int E = in_sizes[0] / 2;            // edge_index is (2, E) int32
    const int N = in_sizes[1] / EMB_DIM;      // embedding is (N, 128) f32
    const int nbuck = (N + FINE_W - 1) >> FINE_BITS;   // 1563 for N=100000

    const int* edge_index = (const int*)d_in[0];
    const int* row = edge_index;              // sources
    const int* col = edge_index + E;          // destinations
    const float* emb = (const float*)d_in[1];
    float* out = (float*)d_out;

    // slack per bucket: mean + 25% + 1024 (>>10 sigma for random edges),
    // rounded to x4 (deg uint loads), clamped to K3 LDS sort capacity.
    const int expected = (int)(((long long)E * FINE_W + N - 1) / N);
    int slack = expected + (expected >> 2) + 1024;
    slack = (slack + 3) & ~3;
    if (slack > MAX_SLACK) slack = MAX_SLACK;
    const size_t bucketEntries = (size_t)nbuck * slack;

    char* ws = (char*)d_ws;
    size_t off = 0;
    auto alloc = [&](size_t bytes) -> void* {
        off = (off + 255) & ~(size_t)255;
        void* p = ws + off;
        off += bytes;
        return p;
    };

    size_t szEmb16 = (size_t)N * EMB_DIM * 2;
    size_t needCommon = (size_t)MAXB * 8 + (size_t)N * 4 +
                        bucketEntries * 5 + 16 * 256;
    bool useFp16 = (needCommon + szEmb16) <= ws_size;

    int*            colCur    = (int*)alloc((size_t)MAXB * 4);
    int*            rowCur    = (int*)alloc((size_t)MAXB * 4);   // adjacent to colCur
    float*          dis       = (float*)alloc((size_t)N * 4);
    unsigned int*   colBucket = (unsigned int*)alloc(bucketEntries * 4);
    unsigned char*  rowBucket = (unsigned char*)alloc(bucketEntries);
    __half*         emb16     = useFp16 ? (__half*)alloc(szEmb16) : (__half*)nullptr;

    const int nchunks = (E + CHUNK - 1) / CHUNK;
    long long n8 = useFp16 ? (long long)N * EMB_DIM / 8 : 0;
    int cvtBlocks = useFp16 ? (int)((n8 + SB - 1) / SB) : 0;

    // zero both relative cursor arrays (adjacent, MAXB*4 each, 256-aligned)
    hipMemsetAsync(colCur, 0, (size_t)MAXB * 8, stream);

    scatter_cvt_kernel<<<nchunks + cvtBlocks, SB, 0, stream>>>(
        row, col, colCur, rowCur, colBucket, rowBucket,
        emb, emb16, n8, slack, nchunks, E);

    deg_kernel<<<nbuck, 512, 0, stream>>>(rowBucket, rowCur, dis, slack, N);

    if (useFp16) {
        gather_kernel<true><<<nbuck, 512, 0, stream>>>(
            emb16, emb, dis, colBucket, colCur, out, slack, N);
    } else {
        gather_kernel<false><<<nbuck, 512, 0, stream>>>(
            nullptr, emb, dis, colBucket, colCur, out, slack, N);
    }
}